// Round 1
// baseline (240.068 us; speedup 1.0000x reference)
//
#include <hip/hip_runtime.h>

typedef __attribute__((ext_vector_type(8))) short bf16x8;
typedef __attribute__((ext_vector_type(16))) float f32x16;

__device__ __forceinline__ unsigned short f2b(float f) {
  unsigned x = __builtin_bit_cast(unsigned, f);
  x += 0x7fffu + ((x >> 16) & 1u);   // round-to-nearest-even
  return (unsigned short)(x >> 16);
}

// ---------------------------------------------------------------------------
// Kernel 0: W [768][384] fp32 -> Wt [384][768] bf16 (k-contiguous B-frags)
//           Y [128][384] fp32 -> Ybf bf16 + y2[l] fp32
// ---------------------------------------------------------------------------
__global__ __launch_bounds__(256) void k_prep(const float* __restrict__ W,
                                              const float* __restrict__ Y,
                                              unsigned short* __restrict__ Wt,
                                              unsigned short* __restrict__ Ybf,
                                              float* __restrict__ y2) {
  __shared__ unsigned short sT[64][72];
  int b = blockIdx.x;
  if (b < 72) {
    int bk = (b % 12) * 64, bn = (b / 12) * 64;
    int c = threadIdx.x & 63, rr = threadIdx.x >> 6;
#pragma unroll
    for (int i = 0; i < 16; i++) {
      int row = rr * 16 + i;
      sT[row][c] = f2b(W[(size_t)(bk + row) * 384 + bn + c]);
    }
    __syncthreads();
#pragma unroll
    for (int i = 0; i < 16; i++) {
      int row = rr * 16 + i;
      Wt[(size_t)(bn + row) * 768 + bk + c] = sT[c][row];
    }
  } else {
    int t = threadIdx.x;
    for (int i = t; i < 12288; i += 256) {
      float4 v = ((const float4*)Y)[i];
      ushort4 o;
      o.x = f2b(v.x); o.y = f2b(v.y); o.z = f2b(v.z); o.w = f2b(v.w);
      ((ushort4*)Ybf)[i] = o;
    }
    if (t < 128) {
      const float4* row = (const float4*)(Y + (size_t)t * 384);
      float s = 0.f;
#pragma unroll
      for (int j = 0; j < 96; j++) {
        float4 v = row[j];
        s += v.x * v.x + v.y * v.y + v.z * v.z + v.w * v.w;
      }
      y2[t] = s;
    }
  }
}

// ---------------------------------------------------------------------------
// Fused kernel: projected = cls @ W + b, expmap0, write x, then in-kernel
//               xy = x @ Y^T + Poincare distance epilogue -> logits.
//   block: 128 rows, 512 threads (8 waves), grid 256 (1 block/CU).
//   GEMM1: wave tile 64x96 (2x3 of 32x32x16 bf16 MFMA), K-step 64,
//          1-deep register prefetch across RAW s_barriers (no vmcnt drain).
//   GEMM2: x kept as bf16 in LDS (aliases GEMM1 staging), Y staged from L2.
// ---------------------------------------------------------------------------
#define LDS1 72   // GEMM1 staging row stride (64 + 8 pad)
#define LDSX 392  // sX row stride (384 + 8 pad)
#define LDSY 136  // sY row stride (128 + 8 pad)

__global__ __launch_bounds__(512, 2) void k_main(const float* __restrict__ cls,
                                                 const unsigned short* __restrict__ Wt,
                                                 const float* __restrict__ bias,
                                                 const unsigned short* __restrict__ Ybf,
                                                 const float* __restrict__ y2,
                                                 float* __restrict__ xout,
                                                 float* __restrict__ out) {
  // region0: GEMM1 sA[128*72]+sW[384*72] = 36864 shorts, later sX[128*392]=50176
  // region1: sY[128*136] = 17408 shorts
  __shared__ __align__(16) unsigned short sm[50176 + 17408];  // 135168 B
  __shared__ float rs[128][4];
  __shared__ float sF[128];
  __shared__ float sQ[128];  // x2 per row (fp32, stays in LDS)

  unsigned short* sA = sm;
  unsigned short* sW = sm + 9216;
  unsigned short* sX = sm;
  unsigned short* sY = sm + 50176;

  const int tid = threadIdx.x;
  const int bm = blockIdx.x * 128;
  const int wave = tid >> 6, lane = tid & 63;
  const int r = lane & 31, h = lane >> 5;
  const int rg = wave & 1, cg = wave >> 1;  // GEMM1: rows rg*64, cols cg*96

  f32x16 acc[2][3];
#pragma unroll
  for (int i = 0; i < 2; i++)
#pragma unroll
    for (int j = 0; j < 3; j++)
#pragma unroll
      for (int e = 0; e < 16; e++) acc[i][j][e] = 0.f;

  // ---- GEMM1 with 1-deep register prefetch ----
  float4 rA[2][2];
  uint4 rW[6];

  // prologue: issue tile-0 loads
#pragma unroll
  for (int it = 0; it < 2; it++) {
    int c = tid + it * 512, row = c >> 3, kc = c & 7;
    const float* src = cls + (size_t)(bm + row) * 768 + kc * 8;
    rA[it][0] = *(const float4*)(src);
    rA[it][1] = *(const float4*)(src + 4);
  }
#pragma unroll
  for (int it = 0; it < 6; it++) {
    int c = tid + it * 512, row = c >> 3, kc = c & 7;
    rW[it] = *(const uint4*)(Wt + (size_t)row * 768 + kc * 8);
  }

  for (int t = 0; t < 12; t++) {
    // barrier A: everyone done reading LDS tile t-1. Raw barrier: this wave's
    // ds_reads are already consumed (compiler lgkm waits before MFMA), and we
    // must NOT drain vmcnt here or the prefetch dies.
    asm volatile("s_waitcnt lgkmcnt(0)" ::: "memory");
    __builtin_amdgcn_s_barrier();

    // write tile t to LDS (compiler inserts counted vmcnt waits on rA/rW)
#pragma unroll
    for (int it = 0; it < 2; it++) {
      int c = tid + it * 512, row = c >> 3, kc = c & 7;
      uint4 p;
      p.x = (unsigned)f2b(rA[it][0].x) | ((unsigned)f2b(rA[it][0].y) << 16);
      p.y = (unsigned)f2b(rA[it][0].z) | ((unsigned)f2b(rA[it][0].w) << 16);
      p.z = (unsigned)f2b(rA[it][1].x) | ((unsigned)f2b(rA[it][1].y) << 16);
      p.w = (unsigned)f2b(rA[it][1].z) | ((unsigned)f2b(rA[it][1].w) << 16);
      *(uint4*)(sA + row * LDS1 + kc * 8) = p;
    }
#pragma unroll
    for (int it = 0; it < 6; it++) {
      int c = tid + it * 512, row = c >> 3, kc = c & 7;
      *(uint4*)(sW + row * LDS1 + kc * 8) = rW[it];
    }

    // issue tile t+1 loads; they stay in flight through barrier B + MFMA
    if (t < 11) {
      const int k0 = (t + 1) * 64;
#pragma unroll
      for (int it = 0; it < 2; it++) {
        int c = tid + it * 512, row = c >> 3, kc = c & 7;
        const float* src = cls + (size_t)(bm + row) * 768 + k0 + kc * 8;
        rA[it][0] = *(const float4*)(src);
        rA[it][1] = *(const float4*)(src + 4);
      }
#pragma unroll
      for (int it = 0; it < 6; it++) {
        int c = tid + it * 512, row = c >> 3, kc = c & 7;
        rW[it] = *(const uint4*)(Wt + (size_t)row * 768 + k0 + kc * 8);
      }
    }

    // barrier B: tile t visible (our ds_writes drained, vmcnt untouched)
    asm volatile("s_waitcnt lgkmcnt(0)" ::: "memory");
    __builtin_amdgcn_s_barrier();

#pragma unroll
    for (int sub = 0; sub < 4; sub++) {
      const int kk = sub * 16 + h * 8;
      bf16x8 a0 = *(const bf16x8*)(sA + (rg * 64 + r) * LDS1 + kk);
      bf16x8 a1 = *(const bf16x8*)(sA + (rg * 64 + 32 + r) * LDS1 + kk);
      bf16x8 b0 = *(const bf16x8*)(sW + (cg * 96 + r) * LDS1 + kk);
      bf16x8 b1 = *(const bf16x8*)(sW + (cg * 96 + 32 + r) * LDS1 + kk);
      bf16x8 b2 = *(const bf16x8*)(sW + (cg * 96 + 64 + r) * LDS1 + kk);
      acc[0][0] = __builtin_amdgcn_mfma_f32_32x32x16_bf16(a0, b0, acc[0][0], 0, 0, 0);
      acc[0][1] = __builtin_amdgcn_mfma_f32_32x32x16_bf16(a0, b1, acc[0][1], 0, 0, 0);
      acc[0][2] = __builtin_amdgcn_mfma_f32_32x32x16_bf16(a0, b2, acc[0][2], 0, 0, 0);
      acc[1][0] = __builtin_amdgcn_mfma_f32_32x32x16_bf16(a1, b0, acc[1][0], 0, 0, 0);
      acc[1][1] = __builtin_amdgcn_mfma_f32_32x32x16_bf16(a1, b1, acc[1][1], 0, 0, 0);
      acc[1][2] = __builtin_amdgcn_mfma_f32_32x32x16_bf16(a1, b2, acc[1][2], 0, 0, 0);
    }
  }

  // ---- expmap0 epilogue: bias add + per-row ||.||^2 ----
  float bcol[3];
#pragma unroll
  for (int j = 0; j < 3; j++) bcol[j] = bias[cg * 96 + j * 32 + r];

#pragma unroll
  for (int i = 0; i < 2; i++) {
#pragma unroll
    for (int reg = 0; reg < 16; reg++) {
      float s = 0.f;
#pragma unroll
      for (int j = 0; j < 3; j++) {
        float v = acc[i][j][reg] + bcol[j];
        acc[i][j][reg] = v;
        s += v * v;
      }
      s += __shfl_xor(s, 1);
      s += __shfl_xor(s, 2);
      s += __shfl_xor(s, 4);
      s += __shfl_xor(s, 8);
      s += __shfl_xor(s, 16);
      if (r == 0) {
        int rowl = rg * 64 + i * 32 + (reg & 3) + 8 * (reg >> 2) + 4 * h;
        rs[rowl][cg] = s;
      }
    }
  }
  __syncthreads();
  if (tid < 128) {
    float n2 = rs[tid][0] + rs[tid][1] + rs[tid][2] + rs[tid][3];
    float n = fmaxf(sqrtf(n2), 1e-15f);
    float f = tanhf(n) / n;
    sF[tid] = f;
    sQ[tid] = n2 * f * f;  // ||x||^2 in fp32 (clip-sensitivity)
  }
  __syncthreads();

  // scale -> write x to global AND bf16-x into LDS (aliases dead sA/sW)
#pragma unroll
  for (int i = 0; i < 2; i++) {
#pragma unroll
    for (int reg = 0; reg < 16; reg++) {
      int rowl = rg * 64 + i * 32 + (reg & 3) + 8 * (reg >> 2) + 4 * h;
      float f = sF[rowl];
#pragma unroll
      for (int j = 0; j < 3; j++) {
        float v = acc[i][j][reg] * f;
        xout[(size_t)(bm + rowl) * 384 + cg * 96 + j * 32 + r] = v;
        sX[rowl * LDSX + cg * 96 + j * 32 + r] = f2b(v);
      }
    }
  }

  // ---- GEMM2: logits = -poincare_dist(x, Y) ----
  const int rt = 32 * (wave & 3), ct = 64 * (wave >> 2);
  f32x16 acc2[2];
#pragma unroll
  for (int j = 0; j < 2; j++)
#pragma unroll
    for (int e = 0; e < 16; e++) acc2[j][e] = 0.f;

  for (int k0 = 0; k0 < 384; k0 += 128) {
    // sX writes visible (first iter) / prev sY chunk consumed (later iters).
    // Raw barrier: x global stores stay in flight (never drained here).
    asm volatile("s_waitcnt lgkmcnt(0)" ::: "memory");
    __builtin_amdgcn_s_barrier();
#pragma unroll
    for (int c = tid; c < 2048; c += 512) {  // Ybf chunk: 128x128 bf16 (L2-hot)
      int row = c >> 4, kc = c & 15;
      *(uint4*)(sY + row * LDSY + kc * 8) =
          *(const uint4*)(Ybf + (size_t)row * 384 + k0 + kc * 8);
    }
    asm volatile("s_waitcnt lgkmcnt(0)" ::: "memory");
    __builtin_amdgcn_s_barrier();
#pragma unroll
    for (int sub = 0; sub < 8; sub++) {
      const int kk = sub * 16 + h * 8;
      bf16x8 a = *(const bf16x8*)(sX + (rt + r) * LDSX + k0 + kk);
      bf16x8 b0 = *(const bf16x8*)(sY + (ct + r) * LDSY + kk);
      bf16x8 b1 = *(const bf16x8*)(sY + (ct + 32 + r) * LDSY + kk);
      acc2[0] = __builtin_amdgcn_mfma_f32_32x32x16_bf16(a, b0, acc2[0], 0, 0, 0);
      acc2[1] = __builtin_amdgcn_mfma_f32_32x32x16_bf16(a, b1, acc2[1], 0, 0, 0);
    }
  }

  const float CLIP = 0.9999800001f;  // (1 - 1e-5)^2
  float yc[2] = {y2[ct + r], y2[ct + 32 + r]};
#pragma unroll
  for (int reg = 0; reg < 16; reg++) {
    int rowl = rt + (reg & 3) + 8 * (reg >> 2) + 4 * h;
    float xr = sQ[rowl];
#pragma unroll
    for (int j = 0; j < 2; j++) {
      float xy = acc2[j][reg];
      float sq = xr + yc[j] - 2.f * xy;
      float den = 1.f - 2.f * xy + xr * yc[j];
      float ratio = fminf(fmaxf(sq / den, 0.f), CLIP);
      float s = sqrtf(ratio);
      float dist = logf((1.f + s) / (1.f - s));  // 2*atanh(s)
      out[(size_t)(bm + rowl) * 128 + ct + j * 32 + r] = -dist;
    }
  }
}

// ---------------------------------------------------------------------------
extern "C" void kernel_launch(void* const* d_in, const int* in_sizes, int n_in,
                              void* d_out, int out_size, void* d_ws, size_t ws_size,
                              hipStream_t stream) {
  const float* cls  = (const float*)d_in[0];  // [32768][768] fp32
  const float* W    = (const float*)d_in[1];  // [768][384] fp32
  const float* bias = (const float*)d_in[2];  // [384] fp32
  const float* Y    = (const float*)d_in[3];  // [128][384] fp32

  float* out_logits = (float*)d_out;                    // [32768][128] fp32
  float* out_x = out_logits + (size_t)32768 * 128;      // [32768][384] fp32

  float* x2 = (float*)d_ws;                           // (unused now)
  float* y2 = x2 + 32768;                             // 128 fp32
  unsigned short* Wt = (unsigned short*)(y2 + 128);   // [384][768] bf16
  unsigned short* Ybf = Wt + (size_t)384 * 768;       // [128][384] bf16

  k_prep<<<73, 256, 0, stream>>>(W, Y, Wt, Ybf, y2);
  k_main<<<256, 512, 0, stream>>>(cls, Wt, bias, Ybf, y2, out_x, out_logits);
}